// Round 9
// baseline (12378.799 us; speedup 1.0000x reference)
//
#include <hip/hip_runtime.h>
#include <cstdint>
#include <cstddef>

typedef unsigned short u16;
typedef __bf16 bf16_t;
typedef bf16_t bf16x8 __attribute__((ext_vector_type(8)));
typedef float f32x4 __attribute__((ext_vector_type(4)));

static constexpr int HID    = 512;
static constexpr int BATCH  = 1024;
static constexpr int NSTEPS = 95;   // T + future - 1 = 64 + 31
static constexpr int T_OBS  = 64;
static constexpr int OUTW   = 190;  // 2 * NSTEPS

// ---------- helpers ----------
__device__ __forceinline__ u16 f2bf(float x) {
  union { float f; uint32_t u; } c; c.f = x;
  uint32_t r = c.u + 0x7fffu + ((c.u >> 16) & 1u);   // RNE
  return (u16)(r >> 16);
}
__device__ __forceinline__ float bf2f(u16 h) {
  union { uint32_t u; float f; } c; c.u = ((uint32_t)h) << 16;
  return c.f;
}
__device__ __forceinline__ float sigm(float x) { return 1.f / (1.f + __expf(-x)); }
__device__ __forceinline__ float tanh_fast(float x) {
  float ax = fabsf(x);
  float t  = __expf(-2.f * ax);
  float r  = (1.f - t) / (1.f + t);
  return x < 0.f ? -r : r;
}

typedef __attribute__((address_space(1))) const uint32_t glb_u32;
typedef __attribute__((address_space(3))) uint32_t lds_u32;
__device__ __forceinline__ void glds16(const void* g, void* l) {
  __builtin_amdgcn_global_load_lds((glb_u32*)g, (lds_u32*)l, 16, 0, 0);
}

// ---------- weight prep (swizzled-interleaved panels, R8-proven) ----------
__global__ void prep_btx1(const float* __restrict__ Whh1, u16* __restrict__ Bt) {
  int idx = blockIdx.x * 256 + threadIdx.x;       // 2048 * 1024
  int n = idx >> 10, t = idx & 1023;
  int blk = t >> 7, slot = (t >> 3) & 15, e = t & 7;
  int ch = slot ^ (n & 15);
  int k = blk * 64 + (ch & 7) * 8 + e;
  int r = (n & 3) * HID + (n >> 2);
  float v = Whh1[r * HID + k];
  u16 hi = f2bf(v);
  Bt[idx] = (ch < 8) ? hi : f2bf(v - bf2f(hi));
}
__global__ void prep_btx2(const float* __restrict__ Wih2, const float* __restrict__ Whh2,
                          u16* __restrict__ Bt) {
  int idx = blockIdx.x * 256 + threadIdx.x;       // 2048 * 2048
  int n = idx >> 11, t = idx & 2047;
  int blk = t >> 7, slot = (t >> 3) & 15, e = t & 7;
  int ch = slot ^ (n & 15);
  int k = blk * 64 + (ch & 7) * 8 + e;            // 0..1023
  int r = (n & 3) * HID + (n >> 2);
  float v = (k < 512) ? Wih2[r * HID + k] : Whh2[r * HID + (k - 512)];
  u16 hi = f2bf(v);
  Bt[idx] = (ch < 8) ? hi : f2bf(v - bf2f(hi));
}
__global__ void prep_small(const float* __restrict__ b1, const float* __restrict__ b2,
                           const float* __restrict__ Wih1,
                           float* __restrict__ b1p, float* __restrict__ b2p,
                           float* __restrict__ w1p) {
  int n = blockIdx.x * 256 + threadIdx.x;
  if (n >= 2048) return;
  int r = (n & 3) * HID + (n >> 2);
  b1p[n] = b1[r];
  b2p[n] = b2[r];
  w1p[2 * n + 0] = Wih1[2 * r + 0];
  w1p[2 * n + 1] = Wih1[2 * r + 1];
}
__global__ void init_out(const float* __restrict__ bl, float* __restrict__ out) {
  int i = blockIdx.x * 256 + threadIdx.x;
  if (i < BATCH * OUTW) out[i] = bl[i & 1];
}

// ---------- device-scope grid barrier (sense via monotonic generation) ----------
__device__ __forceinline__ void gbar(uint32_t* cnt, uint32_t* gen, uint32_t target) {
  __threadfence();                 // release: publish H/out writes
  __syncthreads();
  if (threadIdx.x == 0) {
    if (atomicAdd(cnt, 1u) == 511u) {
      atomicExch(cnt, 0u);
      __threadfence();
      atomicAdd(gen, 1u);          // release the phase
    } else {
      while (atomicAdd(gen, 0u) <= target) __builtin_amdgcn_s_sleep(2);
    }
  }
  __syncthreads();
  __threadfence();                 // acquire: invalidate stale cached lines
}

// ---------- fused gate-GEMM + LSTM cell (persistent-C version) ----------
#define MFMA_(A, B, C) C = __builtin_amdgcn_mfma_f32_16x16x32_bf16(A, B, C, 0, 0, 0)
#define KKBODY(KKC)                                                             \
  {                                                                             \
    const int so_ = sl0 ^ ((KKC) ? 64 : 0);                                     \
    const bf16x8 ah0_ = *(const bf16x8*)(Asb + arow +     0 + so_);             \
    const bf16x8 ah1_ = *(const bf16x8*)(Asb + arow +  4096 + so_);             \
    const bf16x8 ah2_ = *(const bf16x8*)(Asb + arow +  8192 + so_);             \
    const bf16x8 ah3_ = *(const bf16x8*)(Asb + arow + 12288 + so_);             \
    const bf16x8 bh0_ = *(const bf16x8*)(Bsb + brow +     0 + so_);             \
    const bf16x8 bh1_ = *(const bf16x8*)(Bsb + brow +  4096 + so_);             \
    MFMA_(bh0_, ah0_, acc00); MFMA_(bh0_, ah1_, acc01);                         \
    MFMA_(bh0_, ah2_, acc02); MFMA_(bh0_, ah3_, acc03);                         \
    MFMA_(bh1_, ah0_, acc10); MFMA_(bh1_, ah1_, acc11);                         \
    MFMA_(bh1_, ah2_, acc12); MFMA_(bh1_, ah3_, acc13);                         \
    const bf16x8 bl0_ = *(const bf16x8*)(Bsb + brow +     0 + (so_ ^ 128));     \
    const bf16x8 bl1_ = *(const bf16x8*)(Bsb + brow +  4096 + (so_ ^ 128));     \
    MFMA_(bl0_, ah0_, acc00); MFMA_(bl0_, ah1_, acc01);                         \
    MFMA_(bl0_, ah2_, acc02); MFMA_(bl0_, ah3_, acc03);                         \
    MFMA_(bl1_, ah0_, acc10); MFMA_(bl1_, ah1_, acc11);                         \
    MFMA_(bl1_, ah2_, acc12); MFMA_(bl1_, ah3_, acc13);                         \
    const bf16x8 al0_ = *(const bf16x8*)(Asb + arow +     0 + (so_ ^ 128));     \
    const bf16x8 al1_ = *(const bf16x8*)(Asb + arow +  4096 + (so_ ^ 128));     \
    const bf16x8 al2_ = *(const bf16x8*)(Asb + arow +  8192 + (so_ ^ 128));     \
    const bf16x8 al3_ = *(const bf16x8*)(Asb + arow + 12288 + (so_ ^ 128));     \
    MFMA_(bh0_, al0_, acc00); MFMA_(bh0_, al1_, acc01);                         \
    MFMA_(bh0_, al2_, acc02); MFMA_(bh0_, al3_, acc03);                         \
    MFMA_(bh1_, al0_, acc10); MFMA_(bh1_, al1_, acc11);                         \
    MFMA_(bh1_, al2_, acc12); MFMA_(bh1_, al3_, acc13);                         \
  }

#define EPI(I, J, ACC, CREG)                                                    \
  {                                                                             \
    const int hl_ = wn * 8 + (I) * 4 + lq;                                      \
    const int hg_ = hg0 + hl_;                                                  \
    const int ml_ = wm * 64 + (J) * 16 + l15;                                   \
    const int mg_ = mg0 + ml_;                                                  \
    const float4 b4_ = *(const float4*)(bias + 4 * hg_);                        \
    float g0_ = ACC[0] + b4_.x, g1_ = ACC[1] + b4_.y;                           \
    float g2_ = ACC[2] + b4_.z, g3_ = ACC[3] + b4_.w;                           \
    if (HASX) {                                                                 \
      const float x0_ = xe_[(size_t)mg_ * xs_ + 0];                             \
      const float x1_ = xe_[(size_t)mg_ * xs_ + 1];                             \
      const float4 wA_ = *(const float4*)(wih + 8 * hg_);                       \
      const float4 wB_ = *(const float4*)(wih + 8 * hg_ + 4);                   \
      g0_ += x0_ * wA_.x + x1_ * wA_.y;  g1_ += x0_ * wA_.z + x1_ * wA_.w;      \
      g2_ += x0_ * wB_.x + x1_ * wB_.y;  g3_ += x0_ * wB_.z + x1_ * wB_.w;      \
    }                                                                           \
    const float ig_ = sigm(g0_), fg_ = sigm(g1_);                               \
    const float gg_ = tanh_fast(g2_), og_ = sigm(g3_);                          \
    const float cn_ = fg_ * CREG + ig_ * gg_;                                   \
    CREG = cn_;                                                                 \
    const float hn_ = og_ * tanh_fast(cn_);                                     \
    const u16 hi_ = f2bf(hn_);                                                  \
    Hsh[ml_ * 17 + hl_] = hi_;                                                  \
    Hsl[ml_ * 17 + hl_] = f2bf(hn_ - bf2f(hi_));                                \
    if (PROJ) { s0##J += hn_ * wl[hg_]; s1##J += hn_ * wl[HID + hg_]; }         \
  }

// BM=128, BN=64, BK=64, pass-fused, gload_lds staging, C in caller registers.
template <int KTOT, bool HASX, bool PROJ>
__device__ __forceinline__ void run_gemm(
    const u16* Ax0, const u16* Ax1, const u16* Bt, const float* bias,
    const float* xptr, int xstride, bool futx, float* xg,
    const float* wih, u16* Hx, const float* wl, float* oacc, uint32_t* flagp,
    float& c00, float& c10, float& c01, float& c11,
    float& c02, float& c12, float& c03, float& c13,
    int mt, int nt, char* smem) {
  char* const Asb = smem;                    // 128 rows x 256B
  char* const Bsb = smem + 32768;            // 64 rows x 256B
  u16* const AsU = (u16*)Asb;
  u16* const BsU = (u16*)Bsb;

  const int tid = threadIdx.x;
  const int wid = tid >> 6, lane = tid & 63;
  const int wm = wid >> 1, wn = wid & 1;
  const int l15 = lane & 15, lq = lane >> 4;
  const int sl0 = ((lq ^ l15) & 15) << 4;
  const int arow = (wm * 64 + l15) * 256;
  const int brow = (wn * 32 + l15) * 256;
  const int lrow = lane >> 4;
  const int lslot = lane & 15;

  const u16* const aR = Ax0 + (size_t)(mt * 128) * 1024 + (size_t)lrow * 1024 + lslot * 8;
  const u16* const aR2 = (KTOT == 1024)
      ? (Ax1 + (size_t)(mt * 128) * 1024 + (size_t)lrow * 1024 + lslot * 8) : aR;
  constexpr int BRS = 2 * KTOT;
  const u16* const bR = Bt + (size_t)(nt * 64) * BRS + (size_t)lrow * BRS + lslot * 8;

  f32x4 acc00 = {}, acc01 = {}, acc02 = {}, acc03 = {};
  f32x4 acc10 = {}, acc11 = {}, acc12 = {}, acc13 = {};
  constexpr int TOT = KTOT / 64;

  for (int ks = 0; ks < TOT; ++ks) {
    __syncthreads();
    const u16* ap = (KTOT == 1024 && ks >= 8) ? aR2 : aR;
    const int ablk = (KTOT == 1024) ? (ks & 7) : ks;
    const size_t aoff = (size_t)ablk * 128;
#pragma unroll
    for (int i = 0; i < 8; ++i) {
      const int ii = wid * 8 + i;
      glds16(ap + (size_t)(4 * ii) * 1024 + aoff, AsU + ii * 512);
    }
    const size_t boff = (size_t)ks * 128;
#pragma unroll
    for (int j = 0; j < 4; ++j) {
      const int jj = wid * 4 + j;
      glds16(bR + (size_t)(4 * jj) * BRS + boff, BsU + jj * 512);
    }
    __syncthreads();
    KKBODY(0);
    KKBODY(1);
  }

  // ---- epilogue (C in registers) ----
  __syncthreads();                           // LDS free; reuse for H stage + xbuf
  u16* const Hsh = (u16*)smem;               // [128][17]
  u16* const Hsl = Hsh + 128 * 17;           // 8704 B total
  float* const xbuf = (float*)(smem + 8704); // [128][2]

  const int mg0 = mt * 128, hg0 = nt * 16;

  if (HASX) {
    if (futx) {                              // x = out[t-1], written this phase by L2
      if (tid == 0) { while (atomicAdd(flagp, 0u) < 256u) __builtin_amdgcn_s_sleep(2); }
      __syncthreads();
      __threadfence();
      if (tid < 128) {                       // coherent atomic reads -> LDS
        xbuf[tid * 2 + 0] = unsafeAtomicAdd(xg + (size_t)(mg0 + tid) * OUTW + 0, 0.f);
        xbuf[tid * 2 + 1] = unsafeAtomicAdd(xg + (size_t)(mg0 + tid) * OUTW + 1, 0.f);
      }
      __syncthreads();
    }
  }
  const float* xe_ = (HASX && futx) ? ((const float*)xbuf - (size_t)mg0 * 2) : xptr;
  const int xs_ = futx ? 2 : xstride;

  float s00 = 0.f, s01 = 0.f, s02 = 0.f, s03 = 0.f;
  float s10 = 0.f, s11 = 0.f, s12 = 0.f, s13 = 0.f;

  EPI(0, 0, acc00, c00); EPI(1, 0, acc10, c10);
  EPI(0, 1, acc01, c01); EPI(1, 1, acc11, c11);
  EPI(0, 2, acc02, c02); EPI(1, 2, acc12, c12);
  EPI(0, 3, acc03, c03); EPI(1, 3, acc13, c13);

  if (PROJ) {
    s00 += __shfl_xor(s00, 16); s00 += __shfl_xor(s00, 32);
    s01 += __shfl_xor(s01, 16); s01 += __shfl_xor(s01, 32);
    s02 += __shfl_xor(s02, 16); s02 += __shfl_xor(s02, 32);
    s03 += __shfl_xor(s03, 16); s03 += __shfl_xor(s03, 32);
    s10 += __shfl_xor(s10, 16); s10 += __shfl_xor(s10, 32);
    s11 += __shfl_xor(s11, 16); s11 += __shfl_xor(s11, 32);
    s12 += __shfl_xor(s12, 16); s12 += __shfl_xor(s12, 32);
    s13 += __shfl_xor(s13, 16); s13 += __shfl_xor(s13, 32);
    if (lq == 0) {
      float* o0 = oacc + (size_t)(mg0 + wm * 64 +  0 + l15) * OUTW;
      float* o1 = oacc + (size_t)(mg0 + wm * 64 + 16 + l15) * OUTW;
      float* o2 = oacc + (size_t)(mg0 + wm * 64 + 32 + l15) * OUTW;
      float* o3 = oacc + (size_t)(mg0 + wm * 64 + 48 + l15) * OUTW;
      unsafeAtomicAdd(o0 + 0, s00); unsafeAtomicAdd(o0 + 1, s10);
      unsafeAtomicAdd(o1 + 0, s01); unsafeAtomicAdd(o1 + 1, s11);
      unsafeAtomicAdd(o2 + 0, s02); unsafeAtomicAdd(o2 + 1, s12);
      unsafeAtomicAdd(o3 + 0, s03); unsafeAtomicAdd(o3 + 1, s13);
    }
  }

  __syncthreads();                           // PROJ atomics drained (vmcnt0 at barrier)
  if (PROJ) {
    if (tid == 0) { __threadfence(); atomicAdd(flagp, 1u); }   // signal out[t] ready
  }
#pragma unroll
  for (int q = 0; q < 8; ++q) {              // swizzled Hx writeback (R8-proven)
    const int m = (tid >> 4) + 16 * q;
    const int c = tid & 15;
    const int mg = mg0 + m;
    const int hg = hg0 + c;
    const int kq = hg & 63;
    const int ch = kq >> 3, co = kq & 7;
    const int sw = mg & 15;
    u16* rowp = Hx + (size_t)mg * 1024 + (hg >> 6) * 128;
    rowp[((ch ^ sw) << 3) + co]       = Hsh[m * 17 + c];
    rowp[(((ch | 8) ^ sw) << 3) + co] = Hsl[m * 17 + c];
  }
}

// ---------- persistent kernel: 96 phases {L2(t-1) || L1(t)} ----------
struct PArgs {
  const u16* Bt1; const u16* Bt2;
  u16 *H10, *H11, *H12, *H13;       // H1 ping-pong (4-deep)
  u16 *H20, *H21, *H22, *H23;       // H2 ping-pong
  const float *b1p, *b2p, *w1p, *x, *wl;
  float* out;
  uint32_t* flags; uint32_t* bcnt; uint32_t* bgen;
};

__global__ __launch_bounds__(256, 2) void lstm_persist(PArgs a) {
  __shared__ __align__(16) char smem[49152];
  const int wg = blockIdx.x;                 // 0..511
  const bool isL2 = (wg < 256);
  const int b = isL2 ? wg : (wg - 256);
  // 2M x 4N XCD pinning: group g=b&7 owns (M-half g>>2, N-quarter g&3)
  const int g8 = b & 7;
  const int nq = g8 & 3, mh = g8 >> 2;
  const int jj = b >> 3;                     // 0..31
  const int nt = nq * 8 + (jj & 7);          // 0..31
  const int mt = mh * 4 + (jj >> 3);         // 0..7
  float c00 = 0.f, c10 = 0.f, c01 = 0.f, c11 = 0.f;
  float c02 = 0.f, c12 = 0.f, c03 = 0.f, c13 = 0.f;

#pragma unroll 1
  for (int p = 0; p < 96; ++p) {
    if (isL2) {
      if (p >= 1) {
        const int t = p - 1;
        const int pa = t & 3, pb = (t - 1) & 3;
        const u16* A0 = (pa == 0) ? a.H10 : (pa == 1) ? a.H11 : (pa == 2) ? a.H12 : a.H13;
        const u16* A1 = (pb == 0) ? a.H20 : (pb == 1) ? a.H21 : (pb == 2) ? a.H22 : a.H23;
        u16* HW       = (pa == 0) ? a.H20 : (pa == 1) ? a.H21 : (pa == 2) ? a.H22 : a.H23;
        run_gemm<1024, false, true>(A0, A1, a.Bt2, a.b2p,
            nullptr, 0, false, nullptr, nullptr,
            HW, a.wl, a.out + 2 * t, a.flags + t,
            c00, c10, c01, c11, c02, c12, c03, c13, mt, nt, smem);
      }
    } else {
      if (p <= 94) {
        const int t = p;
        const int pa = t & 3, pb = (t - 1) & 3;
        const u16* A0 = (pb == 0) ? a.H10 : (pb == 1) ? a.H11 : (pb == 2) ? a.H12 : a.H13;
        u16* HW       = (pa == 0) ? a.H10 : (pa == 1) ? a.H11 : (pa == 2) ? a.H12 : a.H13;
        const bool fx = (t >= T_OBS);
        const float* xp = fx ? nullptr : (a.x + 2 * t);
        float* xg = fx ? (a.out + 2 * (t - 1)) : nullptr;
        uint32_t* fp = fx ? (a.flags + (t - 1)) : a.flags;
        run_gemm<512, true, false>(A0, nullptr, a.Bt1, a.b1p,
            xp, 2 * T_OBS, fx, xg, a.w1p,
            HW, nullptr, nullptr, fp,
            c00, c10, c01, c11, c02, c12, c03, c13, mt, nt, smem);
      }
    }
    if (p < 95) gbar(a.bcnt, a.bgen, (uint32_t)p);
  }
}

// ---------- host ----------
extern "C" void kernel_launch(void* const* d_in, const int* in_sizes, int n_in,
                              void* d_out, int out_size, void* d_ws, size_t ws_size,
                              hipStream_t stream) {
  const float* x    = (const float*)d_in[0];
  const float* Wih1 = (const float*)d_in[1];
  const float* Whh1 = (const float*)d_in[2];
  const float* b1   = (const float*)d_in[3];
  const float* Wih2 = (const float*)d_in[4];
  const float* Whh2 = (const float*)d_in[5];
  const float* b2   = (const float*)d_in[6];
  const float* Wl   = (const float*)d_in[7];
  const float* bl   = (const float*)d_in[8];
  float* out = (float*)d_out;
  (void)in_sizes; (void)n_in; (void)out_size; (void)ws_size;

  char* p = (char*)d_ws;
  auto alloc = [&](size_t bytes) -> char* {
    char* r = p; p += (bytes + 255) & ~(size_t)255; return r;
  };
  u16* Bt1 = (u16*)alloc((size_t)2048 * 1024 * 2);   // 4 MB swizzled panel
  u16* Bt2 = (u16*)alloc((size_t)2048 * 2048 * 2);   // 8 MB swizzled panel
  char* state0 = p;
  u16* H1x[4]; u16* H2x[4];
  for (int i = 0; i < 4; ++i) H1x[i] = (u16*)alloc((size_t)BATCH * 1024 * 2);
  for (int i = 0; i < 4; ++i) H2x[i] = (u16*)alloc((size_t)BATCH * 1024 * 2);
  uint32_t* flags = (uint32_t*)alloc(512);           // [95] used
  uint32_t* bcnt  = (uint32_t*)alloc(256);
  uint32_t* bgen  = (uint32_t*)alloc(256);
  size_t state_bytes = (size_t)(p - state0);
  float* b1p = (float*)alloc(2048 * 4);
  float* b2p = (float*)alloc(2048 * 4);
  float* w1p = (float*)alloc(2048 * 2 * 4);

  hipMemsetAsync(state0, 0, state_bytes, stream);    // H=0, flags=0, barrier=0
  init_out<<<(BATCH * OUTW + 255) / 256, 256, 0, stream>>>(bl, out);
  prep_btx1<<<8192, 256, 0, stream>>>(Whh1, Bt1);
  prep_btx2<<<16384, 256, 0, stream>>>(Wih2, Whh2, Bt2);
  prep_small<<<8, 256, 0, stream>>>(b1, b2, Wih1, b1p, b2p, w1p);

  PArgs a{};
  a.Bt1 = Bt1; a.Bt2 = Bt2;
  a.H10 = H1x[0]; a.H11 = H1x[1]; a.H12 = H1x[2]; a.H13 = H1x[3];
  a.H20 = H2x[0]; a.H21 = H2x[1]; a.H22 = H2x[2]; a.H23 = H2x[3];
  a.b1p = b1p; a.b2p = b2p; a.w1p = w1p; a.x = x; a.wl = Wl;
  a.out = out; a.flags = flags; a.bcnt = bcnt; a.bgen = bgen;

  lstm_persist<<<512, 256, 0, stream>>>(a);
}

// Round 10
// 4710.412 us; speedup vs baseline: 2.6280x; 2.6280x over previous
//
#include <hip/hip_runtime.h>
#include <cstdint>
#include <cstddef>

typedef unsigned short u16;
typedef __bf16 bf16_t;
typedef bf16_t bf16x8 __attribute__((ext_vector_type(8)));
typedef float f32x4 __attribute__((ext_vector_type(4)));

static constexpr int HID    = 512;
static constexpr int BATCH  = 1024;
static constexpr int NSTEPS = 95;   // T + future - 1 = 64 + 31
static constexpr int T_OBS  = 64;
static constexpr int OUTW   = 190;  // 2 * NSTEPS

// ---------- helpers ----------
__device__ __forceinline__ u16 f2bf(float x) {
  union { float f; uint32_t u; } c; c.f = x;
  uint32_t r = c.u + 0x7fffu + ((c.u >> 16) & 1u);   // RNE
  return (u16)(r >> 16);
}
__device__ __forceinline__ float bf2f(u16 h) {
  union { uint32_t u; float f; } c; c.u = ((uint32_t)h) << 16;
  return c.f;
}
__device__ __forceinline__ float sigm(float x) { return 1.f / (1.f + __expf(-x)); }
__device__ __forceinline__ float tanh_fast(float x) {
  float ax = fabsf(x);
  float t  = __expf(-2.f * ax);
  float r  = (1.f - t) / (1.f + t);
  return x < 0.f ? -r : r;
}

typedef __attribute__((address_space(1))) const uint32_t glb_u32;
typedef __attribute__((address_space(3))) uint32_t lds_u32;
__device__ __forceinline__ void glds16(const void* g, void* l) {
  __builtin_amdgcn_global_load_lds((glb_u32*)g, (lds_u32*)l, 16, 0, 0);
}

// ---------- weight prep (swizzled-interleaved panels, R8-proven) ----------
__global__ void prep_btx1(const float* __restrict__ Whh1, u16* __restrict__ Bt) {
  int idx = blockIdx.x * 256 + threadIdx.x;       // 2048 * 1024
  int n = idx >> 10, t = idx & 1023;
  int blk = t >> 7, slot = (t >> 3) & 15, e = t & 7;
  int ch = slot ^ (n & 15);
  int k = blk * 64 + (ch & 7) * 8 + e;
  int r = (n & 3) * HID + (n >> 2);
  float v = Whh1[r * HID + k];
  u16 hi = f2bf(v);
  Bt[idx] = (ch < 8) ? hi : f2bf(v - bf2f(hi));
}
__global__ void prep_btx2(const float* __restrict__ Wih2, const float* __restrict__ Whh2,
                          u16* __restrict__ Bt) {
  int idx = blockIdx.x * 256 + threadIdx.x;       // 2048 * 2048
  int n = idx >> 11, t = idx & 2047;
  int blk = t >> 7, slot = (t >> 3) & 15, e = t & 7;
  int ch = slot ^ (n & 15);
  int k = blk * 64 + (ch & 7) * 8 + e;            // 0..1023
  int r = (n & 3) * HID + (n >> 2);
  float v = (k < 512) ? Wih2[r * HID + k] : Whh2[r * HID + (k - 512)];
  u16 hi = f2bf(v);
  Bt[idx] = (ch < 8) ? hi : f2bf(v - bf2f(hi));
}
__global__ void prep_small(const float* __restrict__ b1, const float* __restrict__ b2,
                           const float* __restrict__ Wih1,
                           float* __restrict__ b1p, float* __restrict__ b2p,
                           float* __restrict__ w1p) {
  int n = blockIdx.x * 256 + threadIdx.x;
  if (n >= 2048) return;
  int r = (n & 3) * HID + (n >> 2);
  b1p[n] = b1[r];
  b2p[n] = b2[r];
  w1p[2 * n + 0] = Wih1[2 * r + 0];
  w1p[2 * n + 1] = Wih1[2 * r + 1];
}
__global__ void init_out(const float* __restrict__ bl, float* __restrict__ out) {
  int i = blockIdx.x * 256 + threadIdx.x;
  if (i < BATCH * OUTW) out[i] = bl[i & 1];
}

// ---------- fused gate-GEMM + LSTM cell (+ optional out-projection) ----------
struct GArgs {
  const u16* Ax0; const u16* Ax1;   // A panels (Hx layout); Ax1 = k>=512 (L2)
  const u16* Bt;                    // swizzled weight panel [2048][2*KTOT]
  const float* bias;                // reordered bias [2048]
  const float* xptr; int xstride;   // layer-1 input (2 floats/row)
  const float* wih;                 // reordered Wih1 [2048][2]
  float* CstT;                      // cell state TRANSPOSED [512][1024], RMW
  u16* Hx;                          // output H panel (Hx layout)
  const float* wl;                  // Wl [2][512] original order
  float* oacc;                      // out + 2t (atomic accumulate)
};

#define MFMA_(A, B, C) C = __builtin_amdgcn_mfma_f32_16x16x32_bf16(A, B, C, 0, 0, 0)
#define KKBODY(KKC)                                                             \
  {                                                                             \
    const int so_ = sl0 ^ ((KKC) ? 64 : 0);                                     \
    const bf16x8 ah0_ = *(const bf16x8*)(Asb + arow +     0 + so_);             \
    const bf16x8 ah1_ = *(const bf16x8*)(Asb + arow +  4096 + so_);             \
    const bf16x8 ah2_ = *(const bf16x8*)(Asb + arow +  8192 + so_);             \
    const bf16x8 ah3_ = *(const bf16x8*)(Asb + arow + 12288 + so_);             \
    const bf16x8 bh0_ = *(const bf16x8*)(Bsb + brow +     0 + so_);             \
    const bf16x8 bh1_ = *(const bf16x8*)(Bsb + brow +  4096 + so_);             \
    MFMA_(bh0_, ah0_, acc00); MFMA_(bh0_, ah1_, acc01);                         \
    MFMA_(bh0_, ah2_, acc02); MFMA_(bh0_, ah3_, acc03);                         \
    MFMA_(bh1_, ah0_, acc10); MFMA_(bh1_, ah1_, acc11);                         \
    MFMA_(bh1_, ah2_, acc12); MFMA_(bh1_, ah3_, acc13);                         \
    const bf16x8 bl0_ = *(const bf16x8*)(Bsb + brow +     0 + (so_ ^ 128));     \
    const bf16x8 bl1_ = *(const bf16x8*)(Bsb + brow +  4096 + (so_ ^ 128));     \
    MFMA_(bl0_, ah0_, acc00); MFMA_(bl0_, ah1_, acc01);                         \
    MFMA_(bl0_, ah2_, acc02); MFMA_(bl0_, ah3_, acc03);                         \
    MFMA_(bl1_, ah0_, acc10); MFMA_(bl1_, ah1_, acc11);                         \
    MFMA_(bl1_, ah2_, acc12); MFMA_(bl1_, ah3_, acc13);                         \
    const bf16x8 al0_ = *(const bf16x8*)(Asb + arow +     0 + (so_ ^ 128));     \
    const bf16x8 al1_ = *(const bf16x8*)(Asb + arow +  4096 + (so_ ^ 128));     \
    const bf16x8 al2_ = *(const bf16x8*)(Asb + arow +  8192 + (so_ ^ 128));     \
    const bf16x8 al3_ = *(const bf16x8*)(Asb + arow + 12288 + (so_ ^ 128));     \
    MFMA_(bh0_, al0_, acc00); MFMA_(bh0_, al1_, acc01);                         \
    MFMA_(bh0_, al2_, acc02); MFMA_(bh0_, al3_, acc03);                         \
    MFMA_(bh1_, al0_, acc10); MFMA_(bh1_, al1_, acc11);                         \
    MFMA_(bh1_, al2_, acc12); MFMA_(bh1_, al3_, acc13);                         \
  }

#define EPI(I, J, ACC)                                                          \
  {                                                                             \
    const int hl_ = wn * 8 + (I) * 4 + lq;                                      \
    const int hg_ = hg0 + hl_;                                                  \
    const int ml_ = wm * 64 + (J) * 16 + l15;                                   \
    const int mg_ = mg0 + ml_;                                                  \
    const float4 b4_ = *(const float4*)(bias + 4 * hg_);                        \
    float g0_ = ACC[0] + b4_.x, g1_ = ACC[1] + b4_.y;                           \
    float g2_ = ACC[2] + b4_.z, g3_ = ACC[3] + b4_.w;                           \
    if (HASX) {                                                                 \
      const float x0_ = xptr[(size_t)mg_ * xstride + 0];                        \
      const float x1_ = xptr[(size_t)mg_ * xstride + 1];                        \
      const float4 wA_ = *(const float4*)(wih + 8 * hg_);                       \
      const float4 wB_ = *(const float4*)(wih + 8 * hg_ + 4);                   \
      g0_ += x0_ * wA_.x + x1_ * wA_.y;  g1_ += x0_ * wA_.z + x1_ * wA_.w;      \
      g2_ += x0_ * wB_.x + x1_ * wB_.y;  g3_ += x0_ * wB_.z + x1_ * wB_.w;      \
    }                                                                           \
    const float ig_ = sigm(g0_), fg_ = sigm(g1_);                               \
    const float gg_ = tanh_fast(g2_), og_ = sigm(g3_);                          \
    float* cp_ = CstT + (size_t)hg_ * BATCH + mg_;                              \
    const float cn_ = fg_ * (*cp_) + ig_ * gg_;                                 \
    *cp_ = cn_;                                                                 \
    const float hn_ = og_ * tanh_fast(cn_);                                     \
    const u16 hi_ = f2bf(hn_);                                                  \
    Hsh[ml_ * 17 + hl_] = hi_;                                                  \
    Hsl[ml_ * 17 + hl_] = f2bf(hn_ - bf2f(hi_));                                \
    if (PROJ) { s0##J += hn_ * wl[hg_]; s1##J += hn_ * wl[HID + hg_]; }         \
  }

// BM=128, BN=64, BK=64, pass-fused, global_load_lds staging (zero staging VGPR).
template <int KTOT, bool HASX, bool PROJ>
__device__ __forceinline__ void run_gemm(const GArgs& g, int mt, int nt, char* smem) {
  const u16* const Ax0 = g.Ax0;  const u16* const Ax1 = g.Ax1;
  const u16* const Bt  = g.Bt;
  const float* const bias = g.bias;
  const float* const xptr = g.xptr; const int xstride = g.xstride;
  const float* const wih  = g.wih;
  float* const CstT = g.CstT;
  u16* const Hx = g.Hx;
  const float* const wl = g.wl;
  float* const oacc = g.oacc;

  char* const Asb = smem;                    // 128 rows x 256B
  char* const Bsb = smem + 32768;            // 64 rows x 256B
  u16* const AsU = (u16*)Asb;
  u16* const BsU = (u16*)Bsb;

  const int tid = threadIdx.x;
  const int wid = tid >> 6, lane = tid & 63;
  const int wm = wid >> 1, wn = wid & 1;
  const int l15 = lane & 15, lq = lane >> 4;
  const int sl0 = ((lq ^ l15) & 15) << 4;
  const int arow = (wm * 64 + l15) * 256;
  const int brow = (wn * 32 + l15) * 256;
  const int lrow = lane >> 4;
  const int lslot = lane & 15;

  const u16* const aR = Ax0 + (size_t)(mt * 128) * 1024 + (size_t)lrow * 1024 + lslot * 8;
  const u16* const aR2 = (KTOT == 1024)
      ? (Ax1 + (size_t)(mt * 128) * 1024 + (size_t)lrow * 1024 + lslot * 8) : aR;
  constexpr int BRS = 2 * KTOT;
  const u16* const bR = Bt + (size_t)(nt * 64) * BRS + (size_t)lrow * BRS + lslot * 8;

  f32x4 acc00 = {}, acc01 = {}, acc02 = {}, acc03 = {};
  f32x4 acc10 = {}, acc11 = {}, acc12 = {}, acc13 = {};
  constexpr int TOT = KTOT / 64;

  for (int ks = 0; ks < TOT; ++ks) {
    __syncthreads();
    const u16* ap = (KTOT == 1024 && ks >= 8) ? aR2 : aR;
    const int ablk = (KTOT == 1024) ? (ks & 7) : ks;
    const size_t aoff = (size_t)ablk * 128;
#pragma unroll
    for (int i = 0; i < 8; ++i) {
      const int ii = wid * 8 + i;
      glds16(ap + (size_t)(4 * ii) * 1024 + aoff, AsU + ii * 512);
    }
    const size_t boff = (size_t)ks * 128;
#pragma unroll
    for (int j = 0; j < 4; ++j) {
      const int jj = wid * 4 + j;
      glds16(bR + (size_t)(4 * jj) * BRS + boff, BsU + jj * 512);
    }
    __syncthreads();
    KKBODY(0);
    KKBODY(1);
  }

  // ---- in-register epilogue ----
  __syncthreads();
  u16* const Hsh = (u16*)smem;               // [128][17]
  u16* const Hsl = Hsh + 128 * 17;

  const int mg0 = mt * 128, hg0 = nt * 16;
  float s00 = 0.f, s01 = 0.f, s02 = 0.f, s03 = 0.f;
  float s10 = 0.f, s11 = 0.f, s12 = 0.f, s13 = 0.f;

  EPI(0, 0, acc00); EPI(1, 0, acc10);
  EPI(0, 1, acc01); EPI(1, 1, acc11);
  EPI(0, 2, acc02); EPI(1, 2, acc12);
  EPI(0, 3, acc03); EPI(1, 3, acc13);

  if (PROJ) {
    s00 += __shfl_xor(s00, 16); s00 += __shfl_xor(s00, 32);
    s01 += __shfl_xor(s01, 16); s01 += __shfl_xor(s01, 32);
    s02 += __shfl_xor(s02, 16); s02 += __shfl_xor(s02, 32);
    s03 += __shfl_xor(s03, 16); s03 += __shfl_xor(s03, 32);
    s10 += __shfl_xor(s10, 16); s10 += __shfl_xor(s10, 32);
    s11 += __shfl_xor(s11, 16); s11 += __shfl_xor(s11, 32);
    s12 += __shfl_xor(s12, 16); s12 += __shfl_xor(s12, 32);
    s13 += __shfl_xor(s13, 16); s13 += __shfl_xor(s13, 32);
    if (lq == 0) {
      float* o0 = oacc + (size_t)(mg0 + wm * 64 +  0 + l15) * OUTW;
      float* o1 = oacc + (size_t)(mg0 + wm * 64 + 16 + l15) * OUTW;
      float* o2 = oacc + (size_t)(mg0 + wm * 64 + 32 + l15) * OUTW;
      float* o3 = oacc + (size_t)(mg0 + wm * 64 + 48 + l15) * OUTW;
      unsafeAtomicAdd(o0 + 0, s00); unsafeAtomicAdd(o0 + 1, s10);
      unsafeAtomicAdd(o1 + 0, s01); unsafeAtomicAdd(o1 + 1, s11);
      unsafeAtomicAdd(o2 + 0, s02); unsafeAtomicAdd(o2 + 1, s12);
      unsafeAtomicAdd(o3 + 0, s03); unsafeAtomicAdd(o3 + 1, s13);
    }
  }

  __syncthreads();                           // H stage complete
#pragma unroll
  for (int q = 0; q < 8; ++q) {              // swizzled Hx writeback (R8-proven)
    const int m = (tid >> 4) + 16 * q;
    const int c = tid & 15;
    const int mg = mg0 + m;
    const int hg = hg0 + c;
    const int kq = hg & 63;
    const int ch = kq >> 3, co = kq & 7;
    const int sw = mg & 15;
    u16* rowp = Hx + (size_t)mg * 1024 + (hg >> 6) * 128;
    rowp[((ch ^ sw) << 3) + co]       = Hsh[m * 17 + c];
    rowp[(((ch | 8) ^ sw) << 3) + co] = Hsl[m * 17 + c];
  }
}

// 2D XCD pinning: XCD g8=b&7 owns mt in [ (g8>>2)*4, +4 ) and nt in [ (g8&3)*8, +8 )
// -> per-XCD footprint = A-half + B-slice + C-slice (fits 4MB L2); consistent
// across all kernels so H writer/reader XCD groups coincide.
#define TILE_MAP(b)                                                            \
  const int g8_ = (b) & 7, j_ = (b) >> 3;                                      \
  const int nt = (g8_ & 3) * 8 + (j_ & 7);                                     \
  const int mt = (g8_ >> 2) * 4 + (j_ >> 3);

template <int KTOT, bool HASX, bool PROJ>
__global__ __launch_bounds__(256, 2) void step_single(GArgs ga) {
  __shared__ __align__(16) char smem[49152];
  TILE_MAP(blockIdx.x);
  run_gemm<KTOT, HASX, PROJ>(ga, mt, nt, smem);
}

// grid 512: bid<256 -> L2(t) (+proj), else -> L1(t+1)  (independent GEMMs)
__global__ __launch_bounds__(256, 2) void step_fused(GArgs g2, GArgs g1) {
  __shared__ __align__(16) char smem[49152];
  int bid = blockIdx.x;
  int b = (bid < 256) ? bid : bid - 256;
  TILE_MAP(b);
  if (bid < 256) run_gemm<1024, false, true>(g2, mt, nt, smem);
  else           run_gemm<512, true, false>(g1, mt, nt, smem);
}

// Future-step pair: L1(t) produces H1(t) -> per-mt flag; L2(t) consumes.
// All 512 WGs co-resident (launch_bounds(256,2)) -> producers never starve.
__global__ __launch_bounds__(256, 2) void step_pair(GArgs g1, GArgs g2,
                                                    uint32_t* fcnt) {
  __shared__ __align__(16) char smem[49152];
  int bid = blockIdx.x;
  int b = (bid < 256) ? bid : bid - 256;
  TILE_MAP(b);
  if (bid < 256) {                           // L1(t) producer
    run_gemm<512, true, false>(g1, mt, nt, smem);
    __syncthreads();                         // all waves' Hx stores drained
    if (threadIdx.x == 0) {
      __threadfence();                       // wb dirty L2 lines (R9-validated)
      atomicAdd(&fcnt[mt], 1u);
    }
  } else {                                   // L2(t) consumer (+proj)
    if (threadIdx.x == 0) {
      while (__hip_atomic_load(&fcnt[mt], __ATOMIC_RELAXED,
                               __HIP_MEMORY_SCOPE_AGENT) < 32u)
        __builtin_amdgcn_s_sleep(16);
    }
    __syncthreads();
    __threadfence();                         // invalidate stale cached lines
    run_gemm<1024, false, true>(g2, mt, nt, smem);
  }
}

// ---------- host ----------
extern "C" void kernel_launch(void* const* d_in, const int* in_sizes, int n_in,
                              void* d_out, int out_size, void* d_ws, size_t ws_size,
                              hipStream_t stream) {
  const float* x    = (const float*)d_in[0];
  const float* Wih1 = (const float*)d_in[1];
  const float* Whh1 = (const float*)d_in[2];
  const float* b1   = (const float*)d_in[3];
  const float* Wih2 = (const float*)d_in[4];
  const float* Whh2 = (const float*)d_in[5];
  const float* b2   = (const float*)d_in[6];
  const float* Wl   = (const float*)d_in[7];
  const float* bl   = (const float*)d_in[8];
  float* out = (float*)d_out;
  (void)in_sizes; (void)n_in; (void)out_size; (void)ws_size;

  char* p = (char*)d_ws;
  auto alloc = [&](size_t bytes) -> char* {
    char* r = p; p += (bytes + 255) & ~(size_t)255; return r;
  };
  u16* Bt1 = (u16*)alloc((size_t)2048 * 1024 * 2);   // 4 MB swizzled panel
  u16* Bt2 = (u16*)alloc((size_t)2048 * 2048 * 2);   // 8 MB swizzled panel
  char* state0 = p;
  u16* Hxb[4];                                       // H1x[2], H2x[2] ping-pong
  for (int i = 0; i < 4; ++i) Hxb[i] = (u16*)alloc((size_t)BATCH * 1024 * 2);
  float* C1 = (float*)alloc((size_t)BATCH * HID * 4);  // stored [512][1024]
  float* C2 = (float*)alloc((size_t)BATCH * HID * 4);
  uint32_t* flags = (uint32_t*)alloc(31 * 8 * 4);    // per-tail-step mt counters
  size_t state_bytes = (size_t)(p - state0);
  float* b1p = (float*)alloc(2048 * 4);
  float* b2p = (float*)alloc(2048 * 4);
  float* w1p = (float*)alloc(2048 * 2 * 4);

  hipMemsetAsync(state0, 0, state_bytes, stream);    // H=0, C=0, flags=0
  init_out<<<(BATCH * OUTW + 255) / 256, 256, 0, stream>>>(bl, out);
  prep_btx1<<<8192, 256, 0, stream>>>(Whh1, Bt1);
  prep_btx2<<<16384, 256, 0, stream>>>(Wih2, Whh2, Bt2);
  prep_small<<<8, 256, 0, stream>>>(b1, b2, Wih1, b1p, b2p, w1p);

  auto mkL1 = [&](int t) -> GArgs {
    int par = t & 1, prev = par ^ 1;
    GArgs a{};
    a.Ax0 = Hxb[0 + prev]; a.Ax1 = nullptr;
    a.Bt = Bt1; a.bias = b1p;
    a.xptr = (t < T_OBS) ? (x + 2 * t) : (out + 2 * (t - 1));
    a.xstride = (t < T_OBS) ? (2 * T_OBS) : OUTW;
    a.wih = w1p; a.CstT = C1;
    a.Hx = Hxb[0 + par];
    a.wl = nullptr; a.oacc = nullptr;
    return a;
  };
  auto mkL2 = [&](int t) -> GArgs {
    int par = t & 1, prev = par ^ 1;
    GArgs a{};
    a.Ax0 = Hxb[0 + par];   // k<512: H1(t)
    a.Ax1 = Hxb[2 + prev];  // k>=512: H2(t-1)
    a.Bt = Bt2; a.bias = b2p;
    a.xptr = nullptr; a.xstride = 0; a.wih = nullptr;
    a.CstT = C2;
    a.Hx = Hxb[2 + par];
    a.wl = Wl; a.oacc = out + 2 * t;
    return a;
  };

  // step 0 layer 1
  step_single<512, true, false><<<256, 256, 0, stream>>>(mkL1(0));
  // observed steps: L2(t) and L1(t+1) independent -> one 512-WG dispatch
  for (int t = 0; t < T_OBS - 1; ++t)
    step_fused<<<512, 256, 0, stream>>>(mkL2(t), mkL1(t + 1));
  // last observed L2 (writes out[63])
  step_single<1024, false, true><<<256, 256, 0, stream>>>(mkL2(T_OBS - 1));
  // future steps: one paired dispatch per step (L1 -> flags -> L2)
  for (int t = T_OBS; t < NSTEPS; ++t)
    step_pair<<<512, 256, 0, stream>>>(mkL1(t), mkL2(t),
                                       flags + (size_t)(t - T_OBS) * 8);
}

// Round 11
// 3505.570 us; speedup vs baseline: 3.5312x; 1.3437x over previous
//
#include <hip/hip_runtime.h>
#include <cstdint>
#include <cstddef>

typedef unsigned short u16;
typedef __bf16 bf16_t;
typedef bf16_t bf16x8 __attribute__((ext_vector_type(8)));
typedef float f32x4 __attribute__((ext_vector_type(4)));

static constexpr int HID    = 512;
static constexpr int BATCH  = 1024;
static constexpr int NSTEPS = 95;   // T + future - 1 = 64 + 31
static constexpr int T_OBS  = 64;
static constexpr int OUTW   = 190;  // 2 * NSTEPS

// ---------- helpers ----------
__device__ __forceinline__ u16 f2bf(float x) {
  union { float f; uint32_t u; } c; c.f = x;
  uint32_t r = c.u + 0x7fffu + ((c.u >> 16) & 1u);   // RNE
  return (u16)(r >> 16);
}
__device__ __forceinline__ float bf2f(u16 h) {
  union { uint32_t u; float f; } c; c.u = ((uint32_t)h) << 16;
  return c.f;
}
__device__ __forceinline__ float sigm(float x) { return 1.f / (1.f + __expf(-x)); }
__device__ __forceinline__ float tanh_fast(float x) {
  float ax = fabsf(x);
  float t  = __expf(-2.f * ax);
  float r  = (1.f - t) / (1.f + t);
  return x < 0.f ? -r : r;
}

typedef __attribute__((address_space(1))) const uint32_t glb_u32;
typedef __attribute__((address_space(3))) uint32_t lds_u32;
__device__ __forceinline__ void glds16(const void* g, void* l) {
  __builtin_amdgcn_global_load_lds((glb_u32*)g, (lds_u32*)l, 16, 0, 0);
}

// ---------- weight prep (swizzled-interleaved panels, R8-proven) ----------
__global__ void prep_btx1(const float* __restrict__ Whh1, u16* __restrict__ Bt) {
  int idx = blockIdx.x * 256 + threadIdx.x;       // 2048 * 1024
  int n = idx >> 10, t = idx & 1023;
  int blk = t >> 7, slot = (t >> 3) & 15, e = t & 7;
  int ch = slot ^ (n & 15);
  int k = blk * 64 + (ch & 7) * 8 + e;
  int r = (n & 3) * HID + (n >> 2);
  float v = Whh1[r * HID + k];
  u16 hi = f2bf(v);
  Bt[idx] = (ch < 8) ? hi : f2bf(v - bf2f(hi));
}
__global__ void prep_btx2(const float* __restrict__ Wih2, const float* __restrict__ Whh2,
                          u16* __restrict__ Bt) {
  int idx = blockIdx.x * 256 + threadIdx.x;       // 2048 * 2048
  int n = idx >> 11, t = idx & 2047;
  int blk = t >> 7, slot = (t >> 3) & 15, e = t & 7;
  int ch = slot ^ (n & 15);
  int k = blk * 64 + (ch & 7) * 8 + e;            // 0..1023
  int r = (n & 3) * HID + (n >> 2);
  float v = (k < 512) ? Wih2[r * HID + k] : Whh2[r * HID + (k - 512)];
  u16 hi = f2bf(v);
  Bt[idx] = (ch < 8) ? hi : f2bf(v - bf2f(hi));
}
__global__ void prep_small(const float* __restrict__ b1, const float* __restrict__ b2,
                           const float* __restrict__ Wih1,
                           float* __restrict__ b1p, float* __restrict__ b2p,
                           float* __restrict__ w1p) {
  int n = blockIdx.x * 256 + threadIdx.x;
  if (n >= 2048) return;
  int r = (n & 3) * HID + (n >> 2);
  b1p[n] = b1[r];
  b2p[n] = b2[r];
  w1p[2 * n + 0] = Wih1[2 * r + 0];
  w1p[2 * n + 1] = Wih1[2 * r + 1];
}
__global__ void init_out(const float* __restrict__ bl, float* __restrict__ out) {
  int i = blockIdx.x * 256 + threadIdx.x;
  if (i < BATCH * OUTW) out[i] = bl[i & 1];
}

// ---------- fused gate-GEMM + LSTM cell (+ optional out-projection) ----------
struct GArgs {
  const u16* Ax0; const u16* Ax1;   // A panels (Hx layout); Ax1 = k>=512 (L2)
  const u16* Bt;                    // swizzled weight panel [2048][2*KTOT]
  const float* bias;                // reordered bias [2048]
  const float* xptr; int xstride;   // layer-1 input (2 floats/row)
  const float* wih;                 // reordered Wih1 [2048][2]
  u16* Hx;                          // output H panel (Hx layout)
  float* CstT;                      // cell state TRANSPOSED [512][1024], RMW
  const float* wl;                  // Wl [2][512] original order
  float* oacc;                      // out + 2t (atomic accumulate)
};

#define MFMA_(A, B, C) C = __builtin_amdgcn_mfma_f32_16x16x32_bf16(A, B, C, 0, 0, 0)

// Issue the 16 A + 16 B global_load_lds for K-step KS into buffer BUF.
#define STAGE(KS, BUF)                                                          \
  {                                                                             \
    u16* const AsU_ = (u16*)(smem + (BUF) * 32768);                             \
    u16* const BsU_ = (u16*)(smem + (BUF) * 32768 + 16384);                     \
    const u16* ap_ = (KTOT == 1024 && (KS) >= 8) ? aR2 : aR;                    \
    const size_t aoff_ = (size_t)((KTOT == 1024) ? ((KS) & 7) : (KS)) * 128;    \
    const size_t boff_ = (size_t)(KS) * 128;                                    \
    _Pragma("unroll")                                                           \
    for (int i_ = 0; i_ < 4; ++i_) {                                            \
      const int ii_ = wid * 4 + i_;                                             \
      glds16(ap_ + (size_t)(4 * ii_) * 1024 + aoff_, AsU_ + ii_ * 512);         \
      glds16(bR + (size_t)(4 * ii_) * BRS + boff_, BsU_ + ii_ * 512);           \
    }                                                                           \
  }

// One 32-wide k-slice from buffer BUF: 8 frag reads -> 12 MFMAs (hh + lh + hl).
#define KKBODY(BUF, KKC)                                                        \
  {                                                                             \
    const char* const Ab_ = smem + (BUF) * 32768;                               \
    const char* const Bb_ = Ab_ + 16384;                                        \
    const int so_ = sl0 ^ ((KKC) ? 64 : 0);                                     \
    const bf16x8 ah0_ = *(const bf16x8*)(Ab_ + (wm * 32 +  0 + l15) * 256 + so_);          \
    const bf16x8 ah1_ = *(const bf16x8*)(Ab_ + (wm * 32 + 16 + l15) * 256 + so_);          \
    const bf16x8 bh0_ = *(const bf16x8*)(Bb_ + (wn * 32 +  0 + l15) * 256 + so_);          \
    const bf16x8 bh1_ = *(const bf16x8*)(Bb_ + (wn * 32 + 16 + l15) * 256 + so_);          \
    MFMA_(bh0_, ah0_, acc00); MFMA_(bh0_, ah1_, acc01);                         \
    MFMA_(bh1_, ah0_, acc10); MFMA_(bh1_, ah1_, acc11);                         \
    const bf16x8 bl0_ = *(const bf16x8*)(Bb_ + (wn * 32 +  0 + l15) * 256 + (so_ ^ 128));  \
    const bf16x8 bl1_ = *(const bf16x8*)(Bb_ + (wn * 32 + 16 + l15) * 256 + (so_ ^ 128));  \
    MFMA_(bl0_, ah0_, acc00); MFMA_(bl0_, ah1_, acc01);                         \
    MFMA_(bl1_, ah0_, acc10); MFMA_(bl1_, ah1_, acc11);                         \
    const bf16x8 al0_ = *(const bf16x8*)(Ab_ + (wm * 32 +  0 + l15) * 256 + (so_ ^ 128));  \
    const bf16x8 al1_ = *(const bf16x8*)(Ab_ + (wm * 32 + 16 + l15) * 256 + (so_ ^ 128));  \
    MFMA_(bh0_, al0_, acc00); MFMA_(bh0_, al1_, acc01);                         \
    MFMA_(bh1_, al0_, acc10); MFMA_(bh1_, al1_, acc11);                         \
  }

#define EPI(I, J, ACC)                                                          \
  {                                                                             \
    const int hl_ = wn * 8 + (I) * 4 + lq;                                      \
    const int hg_ = hg0 + hl_;                                                  \
    const int ml_ = wm * 32 + (J) * 16 + l15;                                   \
    const int mg_ = mg0 + ml_;                                                  \
    const float4 b4_ = *(const float4*)(bias + 4 * hg_);                        \
    float g0_ = ACC[0] + b4_.x, g1_ = ACC[1] + b4_.y;                           \
    float g2_ = ACC[2] + b4_.z, g3_ = ACC[3] + b4_.w;                           \
    if (HASX) {                                                                 \
      const float x0_ = xptr[(size_t)mg_ * xstride + 0];                        \
      const float x1_ = xptr[(size_t)mg_ * xstride + 1];                        \
      const float4 wA_ = *(const float4*)(wih + 8 * hg_);                       \
      const float4 wB_ = *(const float4*)(wih + 8 * hg_ + 4);                   \
      g0_ += x0_ * wA_.x + x1_ * wA_.y;  g1_ += x0_ * wA_.z + x1_ * wA_.w;      \
      g2_ += x0_ * wB_.x + x1_ * wB_.y;  g3_ += x0_ * wB_.z + x1_ * wB_.w;      \
    }                                                                           \
    const float ig_ = sigm(g0_), fg_ = sigm(g1_);                               \
    const float gg_ = tanh_fast(g2_), og_ = sigm(g3_);                          \
    float* cp_ = CstT + (size_t)hg_ * BATCH + mg_;                              \
    const float cn_ = fg_ * (*cp_) + ig_ * gg_;                                 \
    *cp_ = cn_;                                                                 \
    const float hn_ = og_ * tanh_fast(cn_);                                     \
    const u16 hi_ = f2bf(hn_);                                                  \
    Hsh[ml_ * 17 + hl_] = hi_;                                                  \
    Hsl[ml_ * 17 + hl_] = f2bf(hn_ - bf2f(hi_));                                \
    if (PROJ) {                                                                 \
      if ((J) == 0) { s0a += hn_ * wl[hg_]; s1a += hn_ * wl[HID + hg_]; }       \
      else          { s0b += hn_ * wl[hg_]; s1b += hn_ * wl[HID + hg_]; }       \
    }                                                                           \
  }

// BM=BN=64, BK=64, pass-fused, DOUBLE-BUFFERED gload_lds with ONE barrier/K-step:
//   STAGE(0); for ks { __syncthreads(); STAGE(ks+1 -> other buf); COMPUTE(ks); }
// The sync at iter k drains loads issued at iter k-1 (one compute-phase of
// latency cover) and orders "all readers done" before the buffer is overwritten.
template <int KTOT, bool HASX, bool PROJ>
__device__ __forceinline__ void run_gemm(const GArgs& g, int mt, int nt, char* smem) {
  const u16* const Ax0 = g.Ax0;  const u16* const Ax1 = g.Ax1;
  const u16* const Bt  = g.Bt;
  const float* const bias = g.bias;
  const float* const xptr = g.xptr; const int xstride = g.xstride;
  const float* const wih  = g.wih;
  float* const CstT = g.CstT;
  u16* const Hx = g.Hx;
  const float* const wl = g.wl;
  float* const oacc = g.oacc;

  const int tid = threadIdx.x;
  const int wid = tid >> 6, lane = tid & 63;
  const int wm = wid >> 1, wn = wid & 1;
  const int l15 = lane & 15, lq = lane >> 4;
  const int sl0 = ((lq ^ l15) & 15) << 4;
  const int lrow = lane >> 4;
  const int lslot = lane & 15;

  const u16* const aR = Ax0 + (size_t)(mt * 64) * 1024 + (size_t)lrow * 1024 + lslot * 8;
  const u16* const aR2 = (KTOT == 1024)
      ? (Ax1 + (size_t)(mt * 64) * 1024 + (size_t)lrow * 1024 + lslot * 8) : aR;
  constexpr int BRS = 2 * KTOT;
  const u16* const bR = Bt + (size_t)(nt * 64) * BRS + (size_t)lrow * BRS + lslot * 8;

  f32x4 acc00 = {}, acc01 = {}, acc10 = {}, acc11 = {};
  constexpr int TOT = KTOT / 64;

  STAGE(0, 0);
  for (int ks = 0; ks < TOT; ++ks) {
    __syncthreads();                 // drains own buf[ks&1] loads (issued last iter)
    const int nb = (ks + 1) & 1;
    if (ks + 1 < TOT) STAGE(ks + 1, nb);
    const int cb = ks & 1;
    KKBODY(cb, 0);
    KKBODY(cb, 1);
  }

  // ---- in-register epilogue ----
  __syncthreads();                   // LDS reads done; reuse for H stage
  u16* const Hsh = (u16*)smem;       // [64][17]
  u16* const Hsl = Hsh + 64 * 17;

  const int mg0 = mt * 64, hg0 = nt * 16;
  float s0a = 0.f, s1a = 0.f, s0b = 0.f, s1b = 0.f;

  EPI(0, 0, acc00); EPI(1, 0, acc10);
  EPI(0, 1, acc01); EPI(1, 1, acc11);

  if (PROJ) {                        // reduce over lq (this wave's 8 h values)
    s0a += __shfl_xor(s0a, 16); s0a += __shfl_xor(s0a, 32);
    s1a += __shfl_xor(s1a, 16); s1a += __shfl_xor(s1a, 32);
    s0b += __shfl_xor(s0b, 16); s0b += __shfl_xor(s0b, 32);
    s1b += __shfl_xor(s1b, 16); s1b += __shfl_xor(s1b, 32);
    if (lq == 0) {
      int mgA = mg0 + wm * 32 + l15;
      unsafeAtomicAdd(&oacc[(size_t)mgA * OUTW + 0], s0a);
      unsafeAtomicAdd(&oacc[(size_t)mgA * OUTW + 1], s1a);
      int mgB = mgA + 16;
      unsafeAtomicAdd(&oacc[(size_t)mgB * OUTW + 0], s0b);
      unsafeAtomicAdd(&oacc[(size_t)mgB * OUTW + 1], s1b);
    }
  }

  __syncthreads();                   // H stage complete
#pragma unroll
  for (int q = 0; q < 4; ++q) {      // swizzled Hx writeback (R8-proven formula)
    const int m = (tid >> 4) + 16 * q;       // 0..63
    const int c = tid & 15;
    const int mg = mg0 + m;
    const int hg = hg0 + c;
    const int kq = hg & 63;
    const int ch = kq >> 3, co = kq & 7;
    const int sw = mg & 15;
    u16* rowp = Hx + (size_t)mg * 1024 + (hg >> 6) * 128;
    rowp[((ch ^ sw) << 3) + co]       = Hsh[m * 17 + c];
    rowp[(((ch | 8) ^ sw) << 3) + co] = Hsl[m * 17 + c];
  }
}

// 2D XCD pinning over the 16mt x 32nt tile grid: XCD g8 owns mt in
// [(g8>>2)*8,+8) and nt in [(g8&3)*8,+8) -> consistent writer/reader XCDs.
#define TILE_MAP(b)                                                            \
  const int g8_ = (b) & 7, j_ = (b) >> 3;                                      \
  const int nt = (g8_ & 3) * 8 + (j_ & 7);                                     \
  const int mt = (g8_ >> 2) * 8 + (j_ >> 3);

template <int KTOT, bool HASX, bool PROJ>
__global__ __launch_bounds__(256, 2) void step_single(GArgs ga) {
  __shared__ __align__(16) char smem[65536];
  TILE_MAP(blockIdx.x);
  run_gemm<KTOT, HASX, PROJ>(ga, mt, nt, smem);
}

// grid 1024: bid<512 -> L2(t) (+proj), else -> L1(t+1)  (independent GEMMs)
__global__ __launch_bounds__(256, 2) void step_fused(GArgs g2, GArgs g1) {
  __shared__ __align__(16) char smem[65536];
  int bid = blockIdx.x;
  int b = bid & 511;
  TILE_MAP(b);
  if (bid < 512) run_gemm<1024, false, true>(g2, mt, nt, smem);
  else           run_gemm<512, true, false>(g1, mt, nt, smem);
}

// ---------- host ----------
extern "C" void kernel_launch(void* const* d_in, const int* in_sizes, int n_in,
                              void* d_out, int out_size, void* d_ws, size_t ws_size,
                              hipStream_t stream) {
  const float* x    = (const float*)d_in[0];
  const float* Wih1 = (const float*)d_in[1];
  const float* Whh1 = (const float*)d_in[2];
  const float* b1   = (const float*)d_in[3];
  const float* Wih2 = (const float*)d_in[4];
  const float* Whh2 = (const float*)d_in[5];
  const float* b2   = (const float*)d_in[6];
  const float* Wl   = (const float*)d_in[7];
  const float* bl   = (const float*)d_in[8];
  float* out = (float*)d_out;
  (void)in_sizes; (void)n_in; (void)out_size; (void)ws_size;

  char* p = (char*)d_ws;
  auto alloc = [&](size_t bytes) -> char* {
    char* r = p; p += (bytes + 255) & ~(size_t)255; return r;
  };
  u16* Bt1 = (u16*)alloc((size_t)2048 * 1024 * 2);   // 4 MB swizzled panel
  u16* Bt2 = (u16*)alloc((size_t)2048 * 2048 * 2);   // 8 MB swizzled panel
  char* state0 = p;
  u16* Hxb[4];                                       // H1x[2], H2x[2] ping-pong
  for (int i = 0; i < 4; ++i) Hxb[i] = (u16*)alloc((size_t)BATCH * 1024 * 2);
  float* C1 = (float*)alloc((size_t)BATCH * HID * 4);  // stored [512][1024]
  float* C2 = (float*)alloc((size_t)BATCH * HID * 4);
  size_t state_bytes = (size_t)(p - state0);
  float* b1p = (float*)alloc(2048 * 4);
  float* b2p = (float*)alloc(2048 * 4);
  float* w1p = (float*)alloc(2048 * 2 * 4);

  hipMemsetAsync(state0, 0, state_bytes, stream);    // H=0, C=0
  init_out<<<(BATCH * OUTW + 255) / 256, 256, 0, stream>>>(bl, out);
  prep_btx1<<<8192, 256, 0, stream>>>(Whh1, Bt1);
  prep_btx2<<<16384, 256, 0, stream>>>(Wih2, Whh2, Bt2);
  prep_small<<<8, 256, 0, stream>>>(b1, b2, Wih1, b1p, b2p, w1p);

  auto mkL1 = [&](int t) -> GArgs {
    int par = t & 1, prev = par ^ 1;
    GArgs a{};
    a.Ax0 = Hxb[0 + prev]; a.Ax1 = nullptr;
    a.Bt = Bt1; a.bias = b1p;
    a.xptr = (t < T_OBS) ? (x + 2 * t) : (out + 2 * (t - 1));
    a.xstride = (t < T_OBS) ? (2 * T_OBS) : OUTW;
    a.wih = w1p; a.CstT = C1;
    a.Hx = Hxb[0 + par];
    a.wl = nullptr; a.oacc = nullptr;
    return a;
  };
  auto mkL2 = [&](int t) -> GArgs {
    int par = t & 1, prev = par ^ 1;
    GArgs a{};
    a.Ax0 = Hxb[0 + par];   // k<512: H1(t)
    a.Ax1 = Hxb[2 + prev];  // k>=512: H2(t-1)
    a.Bt = Bt2; a.bias = b2p;
    a.xptr = nullptr; a.xstride = 0; a.wih = nullptr;
    a.CstT = C2;
    a.Hx = Hxb[2 + par];
    a.wl = Wl; a.oacc = out + 2 * t;
    return a;
  };

  // step 0 layer 1
  step_single<512, true, false><<<512, 256, 0, stream>>>(mkL1(0));
  // observed steps: L2(t) and L1(t+1) independent -> one 1024-WG dispatch
  for (int t = 0; t < T_OBS - 1; ++t)
    step_fused<<<1024, 256, 0, stream>>>(mkL2(t), mkL1(t + 1));
  // last observed L2 (writes out[63])
  step_single<1024, false, true><<<512, 256, 0, stream>>>(mkL2(T_OBS - 1));
  // future steps: strict chain L1 -> L2(+proj) -> L1 ...
  for (int t = T_OBS; t < NSTEPS; ++t) {
    step_single<512, true, false><<<512, 256, 0, stream>>>(mkL1(t));
    step_single<1024, false, true><<<512, 256, 0, stream>>>(mkL2(t));
  }
}